// Round 5
// baseline (3211.559 us; speedup 1.0000x reference)
//
#include <hip/hip_runtime.h>
#include <hip/hip_bf16.h>

#define SEQ   256
#define BATCH 64
#define HID   1024
#define EMBD  512
#define VOCAB 128
#define G4    4096
#define HBS   (BATCH * HID)      // 65536 elems per ring slot (128 KB bf16)
#define CNTS  32                 // uints between counters (128 B spacing)

typedef short    bf16x8_t __attribute__((ext_vector_type(8)));
typedef float    f32x4_t  __attribute__((ext_vector_type(4)));
typedef unsigned u32x2_t  __attribute__((ext_vector_type(2)));
using bf16 = __hip_bfloat16;

__device__ __forceinline__ float sigm(float v) { return 1.f / (1.f + expf(-v)); }

// ---- device-coherent ops (write-through / read-at-MALL) ----
__device__ __forceinline__ void cstore8(void* p, u32x2_t d) {
    asm volatile("global_store_dwordx2 %0, %1, off sc0 sc1" :: "v"(p), "v"(d) : "memory");
}
__device__ __forceinline__ void cstore16(void* p, f32x4_t d) {
    asm volatile("global_store_dwordx4 %0, %1, off sc0 sc1" :: "v"(p), "v"(d) : "memory");
}
__device__ __forceinline__ f32x4_t cload16(const void* p) {
    f32x4_t r;
    asm volatile("global_load_dwordx4 %0, %1, off sc0 sc1" : "=v"(r) : "v"(p));
    return r;
}

// ---------------- casts ----------------
__global__ void cast_f32_bf16(const float* __restrict__ src, bf16* __restrict__ dst, int n) {
    int i = blockIdx.x * blockDim.x + threadIdx.x;
    int stride = gridDim.x * blockDim.x;
    for (; i < n; i += stride) dst[i] = __float2bfloat16(src[i]);
}

// ---------------- init: ring slot 0 + counters ----------------
__global__ void init_all(const float* __restrict__ h0,
                         bf16* __restrict__ r0, bf16* __restrict__ r1,
                         unsigned* __restrict__ cnt) {
    int i = blockIdx.x * blockDim.x + threadIdx.x;
    if (i < 24 * CNTS) cnt[i] = 0u;
    int stride = gridDim.x * blockDim.x;
    for (int k = i; k < HBS; k += stride) {
        r0[k] = __float2bfloat16(h0[k]);
        r1[k] = __float2bfloat16(h0[HBS + k]);
    }
}

// ---------------- E = emb @ Wih0.T + b0   [VOCAB][G4] f32 (validated r2-r4) --
__global__ __launch_bounds__(256) void emb_gemm(
    const bf16* __restrict__ emb_bf, const bf16* __restrict__ Wih0_bf,
    const float* __restrict__ b0, float* __restrict__ E) {
    __shared__ float pb[4 * 128 * 17];
    const int tid = threadIdx.x, l = tid & 63, w = tid >> 6;
    const int lm = l & 15, k8 = (l >> 4) << 3;
    const int colbase = blockIdx.x * 16;
    const int gcol = colbase + lm;
    const int kq = w * 128;

    f32x4_t acc[8];
    #pragma unroll
    for (int rt = 0; rt < 8; ++rt) acc[rt] = f32x4_t{0.f, 0.f, 0.f, 0.f};
    bf16x8_t bf[4];
    #pragma unroll
    for (int k = 0; k < 4; ++k)
        bf[k] = *reinterpret_cast<const bf16x8_t*>(Wih0_bf + gcol * EMBD + kq + k * 32 + k8);
    #pragma unroll
    for (int k = 0; k < 4; ++k)
        #pragma unroll
        for (int rt = 0; rt < 8; ++rt) {
            bf16x8_t a = *reinterpret_cast<const bf16x8_t*>(
                emb_bf + (rt * 16 + lm) * EMBD + kq + k * 32 + k8);
            acc[rt] = __builtin_amdgcn_mfma_f32_16x16x32_bf16(a, bf[k], acc[rt], 0, 0, 0);
        }
    const int r0 = (l >> 4) << 2;
    #pragma unroll
    for (int rt = 0; rt < 8; ++rt)
        #pragma unroll
        for (int r = 0; r < 4; ++r)
            pb[(w * 128 + rt * 16 + r0 + r) * 17 + lm] = acc[rt][r];
    __syncthreads();
    #pragma unroll
    for (int i = 0; i < 8; ++i) {
        int p = tid + i * 256;
        int m = p >> 4, cc = p & 15;
        float g = pb[(0 * 128 + m) * 17 + cc] + pb[(1 * 128 + m) * 17 + cc]
                + pb[(2 * 128 + m) * 17 + cc] + pb[(3 * 128 + m) * 17 + cc];
        E[m * G4 + colbase + cc] = g + b0[colbase + cc];
    }
}

// ---------------- persistent 3-group pipelined LSTM --------------------------
// GRP 0 "A" (wg   0.. 63): L0 h-GEMM+act; sg in [0,255]; r0[sg] -> r0[sg+1]
// GRP 2 "B" (wg  64..127): L1 h-GEMM+act; sg in [2,257]; u=sg-2; r1[u],xg[u&3] -> r1[u+1]
// GRP 1 "C" (wg 128..191): L1 x-GEMM;     sg in [1,256]; u=sg-1; r0[sg] -> xg[u&3] (+b1)
template<int GRP>
__device__ __forceinline__ void run_group(
    const int* __restrict__ x, const bf16* __restrict__ W,
    const float* __restrict__ E, const float* __restrict__ b1,
    const float* __restrict__ c0,
    bf16* __restrict__ rSelf, const bf16* __restrict__ rOther,
    float* __restrict__ xg, unsigned* __restrict__ cnt,
    float* __restrict__ out, float* __restrict__ pbuf, int tid, int wg)
{
    const int gwg = wg & 63, hb = gwg * 16;     // 16 h-cols per WG
    const int l = tid & 63, kg = tid >> 6;      // wave = K-slice (256 wide)
    const int lm = l & 15, lk = l >> 4;
    const int m = tid >> 2, hc0 = (tid & 3) * 4;  // act mapping: 4 cols per thread

    unsigned* cA = cnt;
    unsigned* cC = cnt + 8 * CNTS;
    unsigned* cB = cnt + 16 * CNTS;
    unsigned* own = (GRP == 0) ? cA : (GRP == 1) ? cC : cB;

    float creg[4];
    if (GRP != 1) {
        const float* c0l = c0 + (GRP == 2 ? HBS : 0) + m * HID + hb + hc0;
        #pragma unroll
        for (int j = 0; j < 4; ++j) creg[j] = c0l[j];
    }

    const int sg_lo = (GRP == 0) ? 0 : (GRP == 1) ? 1 : 2;
    const int sg_hi = (GRP == 0) ? 255 : (GRP == 1) ? 256 : 257;

    for (int sg = sg_lo; sg <= sg_hi; ++sg) {
        // ---- prefetch (A: E-gather rows; ready before any sync) ----
        f32x4_t epf[4];
        if (GRP == 0) {
            const int xv = x[sg * BATCH + m];
            const float* Ep = E + (size_t)xv * G4 + hb + hc0;
            #pragma unroll
            for (int sec = 0; sec < 4; ++sec)
                epf[sec] = *reinterpret_cast<const f32x4_t*>(Ep + sec * HID);
            asm volatile("" :: "v"(epf[0]), "v"(epf[1]), "v"(epf[2]), "v"(epf[3]));
        }

        // ---- wait ----
        if (tid == 0) {
            for (;;) {
                bool ok = true;
                if (GRP == 0) {
                    #pragma unroll
                    for (int i = 0; i < 8; ++i)
                        ok &= (__hip_atomic_load(cA + i * CNTS, __ATOMIC_RELAXED,
                                                 __HIP_MEMORY_SCOPE_AGENT) >= (unsigned)(sg * 8));
                } else if (GRP == 1) {
                    #pragma unroll
                    for (int i = 0; i < 8; ++i)
                        ok &= (__hip_atomic_load(cA + i * CNTS, __ATOMIC_RELAXED,
                                                 __HIP_MEMORY_SCOPE_AGENT) >= (unsigned)(sg * 8));
                    const int tb = (sg - 4) * 8;
                    if (tb > 0) {
                        #pragma unroll
                        for (int i = 0; i < 8; ++i)
                            ok &= (__hip_atomic_load(cB + i * CNTS, __ATOMIC_RELAXED,
                                                     __HIP_MEMORY_SCOPE_AGENT) >= (unsigned)tb);
                    }
                } else {
                    #pragma unroll
                    for (int i = 0; i < 8; ++i)
                        ok &= (__hip_atomic_load(cC + i * CNTS, __ATOMIC_RELAXED,
                                                 __HIP_MEMORY_SCOPE_AGENT) >= (unsigned)((sg - 1) * 8));
                    const int tb = (sg - 2) * 8;
                    if (tb > 0) {
                        #pragma unroll
                        for (int i = 0; i < 8; ++i)
                            ok &= (__hip_atomic_load(cB + i * CNTS, __ATOMIC_RELAXED,
                                                     __HIP_MEMORY_SCOPE_AGENT) >= (unsigned)tb);
                    }
                }
                if (ok) break;
                __builtin_amdgcn_s_sleep(2);
            }
        }
        __syncthreads();

        // ---- B: issue xg reads early (consumed after GEMM) ----
        f32x4_t xpf[4];
        if (GRP == 2) {
            const float* xp = xg + (size_t)((sg - 2) & 3) * BATCH * G4
                            + (size_t)m * G4 + hb + hc0;
            #pragma unroll
            for (int sec = 0; sec < 4; ++sec) xpf[sec] = cload16(xp + sec * HID);
        }

        // ---- h-GEMM (A operand from ring, W from L2) ----
        const bf16* asrc = (GRP == 0) ? rSelf + (size_t)sg * HBS
                         : (GRP == 1) ? rOther + (size_t)sg * HBS
                                      : rSelf + (size_t)(sg - 2) * HBS;
        {
            f32x4_t acc[4][4];
            #pragma unroll
            for (int mt = 0; mt < 4; ++mt)
                #pragma unroll
                for (int nt = 0; nt < 4; ++nt) acc[mt][nt] = f32x4_t{0.f, 0.f, 0.f, 0.f};

            const bf16* ab = asrc + (size_t)lm * HID + kg * 256 + lk * 8;
            const bf16* wb = W + ((size_t)hb + lm) * HID + kg * 256 + lk * 8;
            #pragma unroll
            for (int kc = 0; kc < 8; ++kc) {
                bf16x8_t av[4], bv[4];
                #pragma unroll
                for (int mt = 0; mt < 4; ++mt)
                    av[mt] = *reinterpret_cast<const bf16x8_t*>(ab + (size_t)mt * 16 * HID + kc * 32);
                #pragma unroll
                for (int nt = 0; nt < 4; ++nt)
                    bv[nt] = *reinterpret_cast<const bf16x8_t*>(wb + ((size_t)nt << 20) + kc * 32);
                #pragma unroll
                for (int mt = 0; mt < 4; ++mt)
                    #pragma unroll
                    for (int nt = 0; nt < 4; ++nt)
                        acc[mt][nt] = __builtin_amdgcn_mfma_f32_16x16x32_bf16(
                            av[mt], bv[nt], acc[mt][nt], 0, 0, 0);
            }
            #pragma unroll
            for (int mt = 0; mt < 4; ++mt)
                #pragma unroll
                for (int nt = 0; nt < 4; ++nt)
                    #pragma unroll
                    for (int r = 0; r < 4; ++r)
                        pbuf[(kg * 64 + mt * 16 + lk * 4 + r) * 68 + nt * 16 + lm]
                            = acc[mt][nt][r];
        }
        __syncthreads();

        // ---- gate assembly ----
        float g[4][4];
        #pragma unroll
        for (int sec = 0; sec < 4; ++sec) {
            f32x4_t s0 = *reinterpret_cast<const f32x4_t*>(&pbuf[(0 * 64 + m) * 68 + sec * 16 + hc0]);
            f32x4_t s1 = *reinterpret_cast<const f32x4_t*>(&pbuf[(1 * 64 + m) * 68 + sec * 16 + hc0]);
            f32x4_t s2 = *reinterpret_cast<const f32x4_t*>(&pbuf[(2 * 64 + m) * 68 + sec * 16 + hc0]);
            f32x4_t s3 = *reinterpret_cast<const f32x4_t*>(&pbuf[(3 * 64 + m) * 68 + sec * 16 + hc0]);
            #pragma unroll
            for (int j = 0; j < 4; ++j) g[sec][j] = s0[j] + s1[j] + s2[j] + s3[j];
        }

        if (GRP == 1) {
            // C: add bias, publish x-gates for B
            float* xd = xg + (size_t)((sg - 1) & 3) * BATCH * G4 + (size_t)m * G4 + hb + hc0;
            #pragma unroll
            for (int sec = 0; sec < 4; ++sec) {
                f32x4_t bb = *reinterpret_cast<const f32x4_t*>(b1 + sec * HID + hb + hc0);
                f32x4_t v;
                #pragma unroll
                for (int j = 0; j < 4; ++j) v[j] = g[sec][j] + bb[j];
                cstore16(xd + sec * HID, v);
            }
        } else {
            if (GRP == 0) {
                #pragma unroll
                for (int sec = 0; sec < 4; ++sec)
                    #pragma unroll
                    for (int j = 0; j < 4; ++j) g[sec][j] += epf[sec][j];
            } else {
                asm volatile("s_waitcnt vmcnt(0)" ::: "memory");
                #pragma unroll
                for (int sec = 0; sec < 4; ++sec)
                    #pragma unroll
                    for (int j = 0; j < 4; ++j) g[sec][j] += xpf[sec][j];
            }
            float hn[4];
            #pragma unroll
            for (int j = 0; j < 4; ++j) {
                float si = sigm(g[0][j]);
                float sf = sigm(g[1][j]);
                float tg = tanhf(g[2][j]);
                float so = sigm(g[3][j]);
                float cn = sf * creg[j] + si * tg;
                hn[j] = so * tanhf(cn);
                creg[j] = cn;
            }
            unsigned short u0 = __builtin_bit_cast(unsigned short, __float2bfloat16(hn[0]));
            unsigned short u1 = __builtin_bit_cast(unsigned short, __float2bfloat16(hn[1]));
            unsigned short u2 = __builtin_bit_cast(unsigned short, __float2bfloat16(hn[2]));
            unsigned short u3 = __builtin_bit_cast(unsigned short, __float2bfloat16(hn[3]));
            u32x2_t pk;
            pk[0] = (unsigned)u0 | ((unsigned)u1 << 16);
            pk[1] = (unsigned)u2 | ((unsigned)u3 << 16);
            const int wslot = (GRP == 0) ? sg + 1 : sg - 1;   // B: u+1 = sg-1
            cstore8(rSelf + (size_t)wslot * HBS + m * HID + hb + hc0, pk);

            const bool last = (GRP == 0) ? (sg == 255) : (sg == 257);
            if (last) {
                float* oh = out + BATCH * VOCAB + (GRP == 0 ? 0 : HBS);
                float* oc = out + BATCH * VOCAB + 2 * HBS + (GRP == 0 ? 0 : HBS);
                #pragma unroll
                for (int j = 0; j < 4; ++j) {
                    oh[m * HID + hb + hc0 + j] = hn[j];
                    oc[m * HID + hb + hc0 + j] = creg[j];
                }
            }
        }

        // ---- arrive ----
        asm volatile("s_waitcnt vmcnt(0)" ::: "memory");
        __syncthreads();
        if (tid == 0)
            __hip_atomic_fetch_add(own + (wg & 7) * CNTS, 1u,
                                   __ATOMIC_RELAXED, __HIP_MEMORY_SCOPE_AGENT);
    }
}

__global__ __launch_bounds__(256, 1) void lstm_persist(
    const int* __restrict__ x,
    const bf16* __restrict__ Whh0, const bf16* __restrict__ Wih1,
    const bf16* __restrict__ Whh1,
    const float* __restrict__ E, const float* __restrict__ b1,
    const float* __restrict__ c0,
    bf16* __restrict__ r0, bf16* __restrict__ r1,
    float* __restrict__ xg, unsigned* __restrict__ cnt,
    float* __restrict__ out)
{
    __shared__ float pbuf[4 * 64 * 68];   // 68 KB
    const int tid = threadIdx.x, wg = blockIdx.x;
    if (wg < 64)
        run_group<0>(x, Whh0, E, b1, c0, r0, nullptr, xg, cnt, out, pbuf, tid, wg);
    else if (wg < 128)
        run_group<2>(x, Whh1, E, b1, c0, r1, r0, xg, cnt, out, pbuf, tid, wg);
    else
        run_group<1>(x, Wih1, E, b1, c0, nullptr, r0, xg, cnt, out, pbuf, tid, wg);
}

// ---------------- FC head ----------------
__global__ void logits_kernel(const float* __restrict__ h, const float* __restrict__ Wfc,
                              const float* __restrict__ bfc, float* __restrict__ out) {
    int t = blockIdx.x * blockDim.x + threadIdx.x;
    if (t >= BATCH * VOCAB) return;
    int m = t >> 7, v = t & 127;
    const float4* hp = reinterpret_cast<const float4*>(h + (size_t)m * HID);
    const float4* wp = reinterpret_cast<const float4*>(Wfc + (size_t)v * HID);
    float acc = 0.f;
    #pragma unroll 4
    for (int k = 0; k < HID / 4; ++k) {
        float4 a = hp[k], w = wp[k];
        acc += a.x * w.x + a.y * w.y + a.z * w.z + a.w * w.w;
    }
    out[t] = acc + bfc[v];
}

// ---------------- launch ----------------
extern "C" void kernel_launch(void* const* d_in, const int* in_sizes, int n_in,
                              void* d_out, int out_size, void* d_ws, size_t ws_size,
                              hipStream_t stream) {
    const int*   x    = (const int*)d_in[0];
    const float* h0   = (const float*)d_in[1];
    const float* c0   = (const float*)d_in[2];
    const float* emb  = (const float*)d_in[3];
    const float* Wih0 = (const float*)d_in[4];
    const float* Whh0 = (const float*)d_in[5];
    const float* b0   = (const float*)d_in[6];
    const float* Wih1 = (const float*)d_in[7];
    const float* Whh1 = (const float*)d_in[8];
    const float* b1   = (const float*)d_in[9];
    const float* Wfc  = (const float*)d_in[10];
    const float* bfc  = (const float*)d_in[11];
    float* out = (float*)d_out;

    char* ws = (char*)d_ws;
    size_t off = 0;
    auto alloc = [&](size_t bytes) -> void* {
        void* p = ws + off;
        off += (bytes + 255) & ~(size_t)255;
        return p;
    };
    bf16*  Whh0_bf = (bf16*)alloc((size_t)G4 * HID * 2);
    bf16*  Wih1_bf = (bf16*)alloc((size_t)G4 * HID * 2);
    bf16*  Whh1_bf = (bf16*)alloc((size_t)G4 * HID * 2);
    float* E       = (float*)alloc((size_t)VOCAB * G4 * 4);
    bf16*  r0      = (bf16*)alloc((size_t)(SEQ + 1) * HBS * 2);   // 32.9 MB
    bf16*  r1      = (bf16*)alloc((size_t)(SEQ + 1) * HBS * 2);   // 32.9 MB
    float* xg      = (float*)alloc((size_t)4 * BATCH * G4 * 4);   // 4 MB, 4-slot ring
    unsigned* cnt  = (unsigned*)alloc(24 * CNTS * 4);
    (void)ws_size; (void)in_sizes; (void)n_in; (void)out_size;

    // precompute-only overlays on ring slots 1.. (consumed before persist
    // writes those slots; rewritten every launch before use)
    bf16* Wih0_bf = (bf16*)(r0 + HBS);     // 4 MB in r0 slots 1..33
    bf16* emb_bf  = (bf16*)(r1 + HBS);     // 128 KB in r1 slot 1

    cast_f32_bf16<<<64,  256, 0, stream>>>(emb,  emb_bf,  VOCAB * EMBD);
    cast_f32_bf16<<<512, 256, 0, stream>>>(Wih0, Wih0_bf, G4 * EMBD);
    cast_f32_bf16<<<512, 256, 0, stream>>>(Whh0, Whh0_bf, G4 * HID);
    cast_f32_bf16<<<512, 256, 0, stream>>>(Wih1, Wih1_bf, G4 * HID);
    cast_f32_bf16<<<512, 256, 0, stream>>>(Whh1, Whh1_bf, G4 * HID);
    init_all<<<64, 256, 0, stream>>>(h0, r0, r1, cnt);
    emb_gemm<<<G4 / 16, 256, 0, stream>>>(emb_bf, Wih0_bf, b0, E);

    lstm_persist<<<192, 256, 0, stream>>>(x, Whh0_bf, Wih1_bf, Whh1_bf,
                                          E, b1, c0, r0, r1, xg, cnt, out);

    logits_kernel<<<(BATCH * VOCAB + 255) / 256, 256, 0, stream>>>(
        out + BATCH * VOCAB + HBS, Wfc, bfc, out);
}

// Round 9
// 3084.458 us; speedup vs baseline: 1.0412x; 1.0412x over previous
//
#include <hip/hip_runtime.h>
#include <hip/hip_bf16.h>

#define SEQ   256
#define BATCH 64
#define HID   1024
#define EMBD  512
#define VOCAB 128
#define G4    4096
#define HBS   (BATCH * HID)      // 65536 elems per ring slot (128 KB bf16)
#define CNTS  32                 // uints between counters (128 B spacing)

typedef short bf16x8_t __attribute__((ext_vector_type(8)));
typedef float f32x4_t  __attribute__((ext_vector_type(4)));
using bf16 = __hip_bfloat16;

__device__ __forceinline__ float sigm(float v) { return 1.f / (1.f + expf(-v)); }

// write-through 4B store (visible at MALL; readers use normal cached loads —
// safe because every ring address is written exactly once per launch)
__device__ __forceinline__ void cstore4(void* p, unsigned d) {
    asm volatile("global_store_dword %0, %1, off sc0 sc1" :: "v"(p), "v"(d) : "memory");
}

// ---------------- casts ----------------
__global__ void cast_f32_bf16(const float* __restrict__ src, bf16* __restrict__ dst, int n) {
    int i = blockIdx.x * blockDim.x + threadIdx.x;
    int stride = gridDim.x * blockDim.x;
    for (; i < n; i += stride) dst[i] = __float2bfloat16(src[i]);
}

// ---------------- init: ring slot 0 + counters ----------------
__global__ void init_all(const float* __restrict__ h0,
                         bf16* __restrict__ r0, bf16* __restrict__ r1,
                         unsigned* __restrict__ cnt) {
    int i = blockIdx.x * blockDim.x + threadIdx.x;
    if (i < 16 * CNTS) cnt[i] = 0u;
    int stride = gridDim.x * blockDim.x;
    for (int k = i; k < HBS; k += stride) {
        r0[k] = __float2bfloat16(h0[k]);
        r1[k] = __float2bfloat16(h0[HBS + k]);
    }
}

// ---------------- E = emb @ Wih0.T + b0   [VOCAB][G4] f32 (validated r2-r5) --
__global__ __launch_bounds__(256) void emb_gemm(
    const bf16* __restrict__ emb_bf, const bf16* __restrict__ Wih0_bf,
    const float* __restrict__ b0, float* __restrict__ E) {
    __shared__ float pb[4 * 128 * 17];
    const int tid = threadIdx.x, l = tid & 63, w = tid >> 6;
    const int lm = l & 15, k8 = (l >> 4) << 3;
    const int colbase = blockIdx.x * 16;
    const int gcol = colbase + lm;
    const int kq = w * 128;

    f32x4_t acc[8];
    #pragma unroll
    for (int rt = 0; rt < 8; ++rt) acc[rt] = f32x4_t{0.f, 0.f, 0.f, 0.f};
    bf16x8_t bf[4];
    #pragma unroll
    for (int k = 0; k < 4; ++k)
        bf[k] = *reinterpret_cast<const bf16x8_t*>(Wih0_bf + gcol * EMBD + kq + k * 32 + k8);
    #pragma unroll
    for (int k = 0; k < 4; ++k)
        #pragma unroll
        for (int rt = 0; rt < 8; ++rt) {
            bf16x8_t a = *reinterpret_cast<const bf16x8_t*>(
                emb_bf + (rt * 16 + lm) * EMBD + kq + k * 32 + k8);
            acc[rt] = __builtin_amdgcn_mfma_f32_16x16x32_bf16(a, bf[k], acc[rt], 0, 0, 0);
        }
    const int r0 = (l >> 4) << 2;
    #pragma unroll
    for (int rt = 0; rt < 8; ++rt)
        #pragma unroll
        for (int r = 0; r < 4; ++r)
            pb[(w * 128 + rt * 16 + r0 + r) * 17 + lm] = acc[rt][r];
    __syncthreads();
    #pragma unroll
    for (int i = 0; i < 8; ++i) {
        int p = tid + i * 256;
        int m = p >> 4, cc = p & 15;
        float g = pb[(0 * 128 + m) * 17 + cc] + pb[(1 * 128 + m) * 17 + cc]
                + pb[(2 * 128 + m) * 17 + cc] + pb[(3 * 128 + m) * 17 + cc];
        E[m * G4 + colbase + cc] = g + b0[colbase + cc];
    }
}

// ---------------- persistent 2-group pipelined LSTM (r4 structure) -----------
// GRP 0 (wg   0..127): layer0, steps s=0..SEQ-1; reads r0[s], writes r0[s+1]
// GRP 1 (wg 128..255): layer1, steps s=1..SEQ (t=s-1); reads r0[s], r1[s-1], writes r1[s]
// DELTA vs r4: h-weights (Whh) LDS-resident (64 KB/WG, XOR-swizzled) instead of
// the asm-forced Breg registers that spilled to scratch (r4: VGPR=120 proved spill).
// GRP1's x-part (Wih1) streams from L2 in-loop.
template<int GRP, int NKC>
__device__ __forceinline__ void run_layer(
    const int* __restrict__ x,
    const bf16* __restrict__ Wx, const bf16* __restrict__ Wh,
    const float* __restrict__ E, const float* __restrict__ b1,
    const float* __restrict__ c0,
    bf16* __restrict__ rSelf, const bf16* __restrict__ rOther,
    unsigned* __restrict__ cnt, float* __restrict__ out,
    float* __restrict__ pbuf, char* __restrict__ Wlds, int tid, int wg)
{
    const int gl = wg & 127;
    const int hb = gl * 8;                       // 8 h-cols per WG
    const int l  = tid & 63, kg = tid >> 6;      // wave = K-slice group
    const int lm = l & 15, lk = l >> 4;
    const int swz = (lm & 7) << 4;

    // gate columns (weight rows): tile nt covers sections 2nt + (lm>>3)
    int gcol[2];
    #pragma unroll
    for (int nt = 0; nt < 2; ++nt)
        gcol[nt] = (2 * nt + (lm >> 3)) * HID + hb + (lm & 7);

    // ---- one-time: stage this WG's Whh slice into LDS (32 rows x 1024 K) ----
    // LDS row r = sec*8 + hcol  <->  global gate-col sec*HID + hb + hcol.
    // Read side uses row = nt*16 + lm, which equals (2nt+(lm>>3))*8 + (lm&7). ✓
    #pragma unroll 4
    for (int i = 0; i < 16; ++i) {
        int chunk = tid + i * 256;               // [0, 4096) 16B chunks
        int row = chunk >> 7, cb = chunk & 127;
        int gc = (row >> 3) * HID + hb + (row & 7);
        bf16x8_t v = *reinterpret_cast<const bf16x8_t*>(Wh + (size_t)gc * HID + cb * 8);
        *reinterpret_cast<bf16x8_t*>(Wlds + row * 2048 + ((cb * 16) ^ ((row & 7) << 4))) = v;
    }
    __syncthreads();

    // wave roles (r4): GRP0: all 4 waves h-part (kbase = kg*256).
    // GRP1: waves 0,1 x-part (Wih1 from L2), waves 2,3 h-part (LDS).
    const bool xwave = (GRP == 1) && (kg < 2);
    const int kbase = (GRP == 0) ? kg * 256 : (kg & 1) * 512;
    const int ldsKbyte = kbase * 2;              // multiples of 512 -> swizzle-safe

    // ---- activation mapping: thread -> (row am, 2 h-cols) (r4 verbatim) ----
    const int am = tid >> 2, cp = tid & 3;
    const int cc0 = cp * 2, col0 = hb + cc0;
    float creg[2];
    creg[0] = c0[GRP * HBS + am * HID + col0];
    creg[1] = c0[GRP * HBS + am * HID + col0 + 1];

    const unsigned* cOwn = cnt + GRP * 8 * CNTS;
    const unsigned* cL0  = cnt;
    unsigned* aOwn = (unsigned*)cOwn;

    const int s_begin = (GRP == 0) ? 0 : 1;
    const int s_end   = (GRP == 0) ? SEQ : SEQ + 1;

    for (int s = s_begin; s < s_end; ++s) {
        // ---- wait phase (r4 verbatim) ----
        if (tid == 0) {
            const unsigned tOwn = (unsigned)(GRP == 0 ? s : s - 1) * 16u;
            const unsigned tL0  = (unsigned)s * 16u;
            for (;;) {
                bool ok = true;
                #pragma unroll
                for (int i = 0; i < 8; ++i)
                    ok &= (__hip_atomic_load(cOwn + i * CNTS, __ATOMIC_RELAXED,
                                             __HIP_MEMORY_SCOPE_AGENT) >= tOwn);
                if (GRP == 1) {
                    #pragma unroll
                    for (int i = 0; i < 8; ++i)
                        ok &= (__hip_atomic_load(cL0 + i * CNTS, __ATOMIC_RELAXED,
                                                 __HIP_MEMORY_SCOPE_AGENT) >= tL0);
                }
                if (ok) break;
                __builtin_amdgcn_s_sleep(2);
            }
        }
        __syncthreads();

        // ---- GEMM: K-slice per wave; A from ring (cached); B from LDS or L2 ----
        const bf16* asrc;
        if (GRP == 0) asrc = rSelf + (size_t)s * HBS;
        else          asrc = xwave ? (rOther + (size_t)s * HBS)
                                   : (rSelf + (size_t)(s - 1) * HBS);

        f32x4_t acc[4][2];
        #pragma unroll
        for (int mt = 0; mt < 4; ++mt)
            #pragma unroll
            for (int nt = 0; nt < 2; ++nt) acc[mt][nt] = f32x4_t{0.f, 0.f, 0.f, 0.f};

        #pragma unroll
        for (int kc = 0; kc < NKC; ++kc) {
            bf16x8_t a[4];
            #pragma unroll
            for (int mt = 0; mt < 4; ++mt)
                a[mt] = *reinterpret_cast<const bf16x8_t*>(
                    asrc + (size_t)(mt * 16 + lm) * HID + kbase + kc * 32 + lk * 8);
            bf16x8_t bv[2];
            #pragma unroll
            for (int nt = 0; nt < 2; ++nt) {
                if (xwave)
                    bv[nt] = *reinterpret_cast<const bf16x8_t*>(
                        Wx + (size_t)gcol[nt] * HID + kbase + kc * 32 + lk * 8);
                else
                    bv[nt] = *reinterpret_cast<const bf16x8_t*>(
                        Wlds + (nt * 16 + lm) * 2048
                             + ((ldsKbyte + kc * 64 + lk * 16) ^ swz));
            }
            #pragma unroll
            for (int mt = 0; mt < 4; ++mt)
                #pragma unroll
                for (int nt = 0; nt < 2; ++nt)
                    acc[mt][nt] = __builtin_amdgcn_mfma_f32_16x16x32_bf16(
                        a[mt], bv[nt], acc[mt][nt], 0, 0, 0);
        }

        // ---- partials -> LDS [wave][m][c] (r4 verbatim) ----
        #pragma unroll
        for (int mt = 0; mt < 4; ++mt)
            #pragma unroll
            for (int nt = 0; nt < 2; ++nt)
                #pragma unroll
                for (int r = 0; r < 4; ++r)
                    pbuf[(kg * 64 + mt * 16 + lk * 4 + r) * 36 + nt * 16 + lm]
                        = acc[mt][nt][r];
        __syncthreads();

        // ---- gate assembly + activation + ring write (r4 verbatim) ----
        float g[4][2];
        #pragma unroll
        for (int sec = 0; sec < 4; ++sec) { g[sec][0] = 0.f; g[sec][1] = 0.f; }
        #pragma unroll
        for (int w4 = 0; w4 < 4; ++w4)
            #pragma unroll
            for (int sec = 0; sec < 4; ++sec) {
                const float* pp = &pbuf[(w4 * 64 + am) * 36 + sec * 8 + cc0];
                g[sec][0] += pp[0];
                g[sec][1] += pp[1];
            }
        if (GRP == 0) {
            const int xv = x[s * BATCH + am];
            const float* Ep = E + (size_t)xv * G4 + col0;
            #pragma unroll
            for (int sec = 0; sec < 4; ++sec) {
                g[sec][0] += Ep[sec * HID];
                g[sec][1] += Ep[sec * HID + 1];
            }
        } else {
            #pragma unroll
            for (int sec = 0; sec < 4; ++sec) {
                g[sec][0] += b1[sec * HID + col0];
                g[sec][1] += b1[sec * HID + col0 + 1];
            }
        }

        float hn[2];
        #pragma unroll
        for (int j = 0; j < 2; ++j) {
            float si = sigm(g[0][j]);
            float sf = sigm(g[1][j]);
            float tg = tanhf(g[2][j]);
            float so = sigm(g[3][j]);
            float cn = sf * creg[j] + si * tg;
            hn[j] = so * tanhf(cn);
            creg[j] = cn;
        }
        unsigned short u0 = __builtin_bit_cast(unsigned short, __float2bfloat16(hn[0]));
        unsigned short u1 = __builtin_bit_cast(unsigned short, __float2bfloat16(hn[1]));
        const int wslot = (GRP == 0) ? s + 1 : s;
        cstore4(rSelf + (size_t)wslot * HBS + am * HID + col0,
                (unsigned)u0 | ((unsigned)u1 << 16));

        const bool last = (GRP == 0) ? (s == SEQ - 1) : (s == SEQ);
        if (last) {
            float* oh = out + BATCH * VOCAB + GRP * HBS;
            float* oc = out + BATCH * VOCAB + 2 * HBS + GRP * HBS;
            oh[am * HID + col0]     = hn[0];
            oh[am * HID + col0 + 1] = hn[1];
            oc[am * HID + col0]     = creg[0];
            oc[am * HID + col0 + 1] = creg[1];
        }

        // ---- arrive phase (r4 verbatim) ----
        asm volatile("s_waitcnt vmcnt(0)" ::: "memory");
        __syncthreads();
        if (tid == 0)
            __hip_atomic_fetch_add(aOwn + (wg & 7) * CNTS, 1u,
                                   __ATOMIC_RELAXED, __HIP_MEMORY_SCOPE_AGENT);
    }
}

__global__ __launch_bounds__(256, 1) void lstm_persist(
    const int* __restrict__ x,
    const bf16* __restrict__ Whh0, const bf16* __restrict__ Wih1,
    const bf16* __restrict__ Whh1,
    const float* __restrict__ E, const float* __restrict__ b1,
    const float* __restrict__ c0,
    bf16* __restrict__ r0, bf16* __restrict__ r1,
    unsigned* __restrict__ cnt, float* __restrict__ out)
{
    __shared__ float pbuf[4 * 64 * 36];   // 36 KB
    __shared__ char  Wlds[65536];         // 64 KB Whh slice -> 100 KB total, 1 WG/CU
    const int tid = threadIdx.x, wg = blockIdx.x;
    if (wg < 128)
        run_layer<0, 8>(x, nullptr, Whh0, E, nullptr, c0, r0, nullptr, cnt, out,
                        pbuf, Wlds, tid, wg);
    else
        run_layer<1, 16>(x, Wih1, Whh1, E, b1, c0, r1, r0, cnt, out,
                         pbuf, Wlds, tid, wg);
}

// ---------------- FC head ----------------
__global__ void logits_kernel(const float* __restrict__ h, const float* __restrict__ Wfc,
                              const float* __restrict__ bfc, float* __restrict__ out) {
    int t = blockIdx.x * blockDim.x + threadIdx.x;
    if (t >= BATCH * VOCAB) return;
    int m = t >> 7, v = t & 127;
    const float4* hp = reinterpret_cast<const float4*>(h + (size_t)m * HID);
    const float4* wp = reinterpret_cast<const float4*>(Wfc + (size_t)v * HID);
    float acc = 0.f;
    #pragma unroll 4
    for (int k = 0; k < HID / 4; ++k) {
        float4 a = hp[k], w = wp[k];
        acc += a.x * w.x + a.y * w.y + a.z * w.z + a.w * w.w;
    }
    out[t] = acc + bfc[v];
}

// ---------------- launch ----------------
extern "C" void kernel_launch(void* const* d_in, const int* in_sizes, int n_in,
                              void* d_out, int out_size, void* d_ws, size_t ws_size,
                              hipStream_t stream) {
    const int*   x    = (const int*)d_in[0];
    const float* h0   = (const float*)d_in[1];
    const float* c0   = (const float*)d_in[2];
    const float* emb  = (const float*)d_in[3];
    const float* Wih0 = (const float*)d_in[4];
    const float* Whh0 = (const float*)d_in[5];
    const float* b0   = (const float*)d_in[6];
    const float* Wih1 = (const float*)d_in[7];
    const float* Whh1 = (const float*)d_in[8];
    const float* b1   = (const float*)d_in[9];
    const float* Wfc  = (const float*)d_in[10];
    const float* bfc  = (const float*)d_in[11];
    float* out = (float*)d_out;

    char* ws = (char*)d_ws;
    size_t off = 0;
    auto alloc = [&](size_t bytes) -> void* {
        void* p = ws + off;
        off += (bytes + 255) & ~(size_t)255;
        return p;
    };
    bf16*  Whh0_bf = (bf16*)alloc((size_t)G4 * HID * 2);
    bf16*  Wih1_bf = (bf16*)alloc((size_t)G4 * HID * 2);
    bf16*  Whh1_bf = (bf16*)alloc((size_t)G4 * HID * 2);
    float* E       = (float*)alloc((size_t)VOCAB * G4 * 4);
    bf16*  r0      = (bf16*)alloc((size_t)(SEQ + 1) * HBS * 2);   // 32.9 MB ring
    bf16*  r1      = (bf16*)alloc((size_t)(SEQ + 1) * HBS * 2);   // 32.9 MB ring
    unsigned* cnt  = (unsigned*)alloc(16 * CNTS * 4);
    bf16* Wih0_bf  = (bf16*)alloc((size_t)G4 * EMBD * 2);   // dedicated (no overlay)
    bf16* emb_bf   = (bf16*)alloc((size_t)VOCAB * EMBD * 2);
    (void)ws_size; (void)in_sizes; (void)n_in; (void)out_size;

    cast_f32_bf16<<<64,  256, 0, stream>>>(emb,  emb_bf,  VOCAB * EMBD);
    cast_f32_bf16<<<512, 256, 0, stream>>>(Wih0, Wih0_bf, G4 * EMBD);
    cast_f32_bf16<<<512, 256, 0, stream>>>(Whh0, Whh0_bf, G4 * HID);
    cast_f32_bf16<<<512, 256, 0, stream>>>(Wih1, Wih1_bf, G4 * HID);
    cast_f32_bf16<<<512, 256, 0, stream>>>(Whh1, Whh1_bf, G4 * HID);
    init_all<<<64, 256, 0, stream>>>(h0, r0, r1, cnt);
    emb_gemm<<<G4 / 16, 256, 0, stream>>>(emb_bf, Wih0_bf, b0, E);

    lstm_persist<<<256, 256, 0, stream>>>(x, Whh0_bf, Wih1_bf, Whh1_bf,
                                          E, b1, c0, r0, r1, cnt, out);

    logits_kernel<<<(BATCH * VOCAB + 255) / 256, 256, 0, stream>>>(
        out + BATCH * VOCAB + HBS, Wfc, bfc, out);
}

// Round 10
// 2695.935 us; speedup vs baseline: 1.1913x; 1.1441x over previous
//
#include <hip/hip_runtime.h>
#include <hip/hip_bf16.h>

#define SEQ   256
#define BATCH 64
#define HID   1024
#define EMBD  512
#define VOCAB 128
#define G4    4096
#define HBS   (BATCH * HID)      // 65536 elems per ring slot (128 KB bf16)
#define CNTS  32                 // uints between counters (128 B spacing)

typedef short bf16x8_t __attribute__((ext_vector_type(8)));
typedef float f32x4_t  __attribute__((ext_vector_type(4)));
using bf16 = __hip_bfloat16;

__device__ __forceinline__ float sigm(float v) { return 1.f / (1.f + expf(-v)); }

// write-through 4B store (visible at MALL; readers use normal cached loads —
// safe because every ring address is written exactly once per launch)
__device__ __forceinline__ void cstore4(void* p, unsigned d) {
    asm volatile("global_store_dword %0, %1, off sc0 sc1" :: "v"(p), "v"(d) : "memory");
}

// ---------------- casts ----------------
__global__ void cast_f32_bf16(const float* __restrict__ src, bf16* __restrict__ dst, int n) {
    int i = blockIdx.x * blockDim.x + threadIdx.x;
    int stride = gridDim.x * blockDim.x;
    for (; i < n; i += stride) dst[i] = __float2bfloat16(src[i]);
}

// ---------------- init: ring slot 0 + counters ----------------
__global__ void init_all(const float* __restrict__ h0,
                         bf16* __restrict__ r0, bf16* __restrict__ r1,
                         unsigned* __restrict__ cnt) {
    int i = blockIdx.x * blockDim.x + threadIdx.x;
    if (i < 16 * CNTS) cnt[i] = 0u;
    int stride = gridDim.x * blockDim.x;
    for (int k = i; k < HBS; k += stride) {
        r0[k] = __float2bfloat16(h0[k]);
        r1[k] = __float2bfloat16(h0[HBS + k]);
    }
}

// ---------------- E = emb @ Wih0.T + b0   [VOCAB][G4] f32 (validated r2-r9) --
__global__ __launch_bounds__(256) void emb_gemm(
    const bf16* __restrict__ emb_bf, const bf16* __restrict__ Wih0_bf,
    const float* __restrict__ b0, float* __restrict__ E) {
    __shared__ float pb[4 * 128 * 17];
    const int tid = threadIdx.x, l = tid & 63, w = tid >> 6;
    const int lm = l & 15, k8 = (l >> 4) << 3;
    const int colbase = blockIdx.x * 16;
    const int gcol = colbase + lm;
    const int kq = w * 128;

    f32x4_t acc[8];
    #pragma unroll
    for (int rt = 0; rt < 8; ++rt) acc[rt] = f32x4_t{0.f, 0.f, 0.f, 0.f};
    bf16x8_t bf[4];
    #pragma unroll
    for (int k = 0; k < 4; ++k)
        bf[k] = *reinterpret_cast<const bf16x8_t*>(Wih0_bf + gcol * EMBD + kq + k * 32 + k8);
    #pragma unroll
    for (int k = 0; k < 4; ++k)
        #pragma unroll
        for (int rt = 0; rt < 8; ++rt) {
            bf16x8_t a = *reinterpret_cast<const bf16x8_t*>(
                emb_bf + (rt * 16 + lm) * EMBD + kq + k * 32 + k8);
            acc[rt] = __builtin_amdgcn_mfma_f32_16x16x32_bf16(a, bf[k], acc[rt], 0, 0, 0);
        }
    const int r0 = (l >> 4) << 2;
    #pragma unroll
    for (int rt = 0; rt < 8; ++rt)
        #pragma unroll
        for (int r = 0; r < 4; ++r)
            pb[(w * 128 + rt * 16 + r0 + r) * 17 + lm] = acc[rt][r];
    __syncthreads();
    #pragma unroll
    for (int i = 0; i < 8; ++i) {
        int p = tid + i * 256;
        int m = p >> 4, cc = p & 15;
        float g = pb[(0 * 128 + m) * 17 + cc] + pb[(1 * 128 + m) * 17 + cc]
                + pb[(2 * 128 + m) * 17 + cc] + pb[(3 * 128 + m) * 17 + cc];
        E[m * G4 + colbase + cc] = g + b0[colbase + cc];
    }
}

// ---- per-wave A staging: 64 rows x 256 K slice -> LDS via global_load_lds ----
// LDS layout [64 rows][512 B] linear; bank swizzle achieved by PRE-SWIZZLING the
// global source chunk: lds chunk (row, kb) holds global chunk (row, kb^(row&7)).
__device__ __forceinline__ void stage_slice(const char* slotB, char* Aregion,
                                            int kByte, int l) {
    #pragma unroll
    for (int i = 0; i < 32; ++i) {
        const int ci  = i * 64 + l;
        const int row = ci >> 5, kb = ci & 31;
        const char* g = slotB + row * 2048 + kByte + ((kb ^ (row & 7)) << 4);
        __builtin_amdgcn_global_load_lds(
            (const __attribute__((address_space(1))) unsigned*)g,
            (__attribute__((address_space(3))) unsigned*)(Aregion + i * 1024),
            16, 0, 0);
    }
}

// ---- K-slice GEMM: A from LDS region, W batched from L2 (16 frags = 64 VGPR) ----
__device__ __forceinline__ void gemm_ks(const char* Aregion, const bf16* W,
                                        int gcol0, int gcol1, int kg,
                                        int lm, int lk, f32x4_t (&acc)[4][2]) {
    bf16x8_t bw[2][8];
    #pragma unroll
    for (int nt = 0; nt < 2; ++nt) {
        const bf16* wb = W + (size_t)(nt == 0 ? gcol0 : gcol1) * HID + kg * 256 + lk * 8;
        #pragma unroll
        for (int kc = 0; kc < 8; ++kc)
            bw[nt][kc] = *reinterpret_cast<const bf16x8_t*>(wb + kc * 32);
    }
    asm volatile("s_waitcnt vmcnt(0)" ::: "memory");   // A-DMA + W loads: one RTT
    __builtin_amdgcn_sched_barrier(0);
    #pragma unroll
    for (int kc = 0; kc < 8; ++kc) {
        bf16x8_t a[4];
        #pragma unroll
        for (int mt = 0; mt < 4; ++mt) {
            const int row = mt * 16 + lm;
            a[mt] = *reinterpret_cast<const bf16x8_t*>(
                Aregion + row * 512 + ((kc * 64 + lk * 16) ^ ((row & 7) << 4)));
        }
        #pragma unroll
        for (int mt = 0; mt < 4; ++mt) {
            acc[mt][0] = __builtin_amdgcn_mfma_f32_16x16x32_bf16(a[mt], bw[0][kc], acc[mt][0], 0, 0, 0);
            acc[mt][1] = __builtin_amdgcn_mfma_f32_16x16x32_bf16(a[mt], bw[1][kc], acc[mt][1], 0, 0, 0);
        }
    }
}

__device__ __forceinline__ void pollge(const unsigned* base, unsigned target, int tid) {
    if (tid == 0) {
        for (;;) {
            bool ok = true;
            #pragma unroll
            for (int i = 0; i < 8; ++i)
                ok &= (__hip_atomic_load(base + i * CNTS, __ATOMIC_RELAXED,
                                         __HIP_MEMORY_SCOPE_AGENT) >= target);
            if (ok) break;
            __builtin_amdgcn_s_sleep(2);
        }
    }
    __syncthreads();
}

// ---------------- persistent 2-group pipelined LSTM --------------------------
// GRP0 (wg   0..127): L0; s=0..255; r0[s] -> r0[s+1]; free-runs (own flags only)
// GRP1 (wg 128..255): L1; s=1..256; x: r0[s] (GRP0 far ahead), h: r1[s-1] -> r1[s]
// Per step: A K-slice staged per-wave-private into LDS (1 RTT), W batched L2.
template<int GRP>
__device__ __forceinline__ void run_layer(
    const int* __restrict__ x,
    const bf16* __restrict__ Wx, const bf16* __restrict__ Wh,
    const float* __restrict__ E, const float* __restrict__ b1,
    const float* __restrict__ c0,
    bf16* __restrict__ rSelf, const bf16* __restrict__ rOther,
    unsigned* __restrict__ cnt, float* __restrict__ out,
    char* __restrict__ Abuf, float* __restrict__ pbuf, int tid, int wg)
{
    const int gl = wg & 127;
    const int hb = gl * 8;                       // 8 h-cols per WG
    const int l  = tid & 63, kg = tid >> 6;      // wave = K-slice group (256 wide)
    const int lm = l & 15, lk = l >> 4;
    char* Areg = Abuf + kg * 32768;              // wave-private 32 KB
    const int kByte = kg * 512;

    // gate columns (weight rows): tile nt covers sections 2nt + (lm>>3)  [r9]
    const int gcol0 = (0 + (lm >> 3)) * HID + hb + (lm & 7);
    const int gcol1 = (2 + (lm >> 3)) * HID + hb + (lm & 7);

    // activation mapping: thread -> (row am, 2 h-cols)  [r9 verbatim]
    const int am = tid >> 2, cp = tid & 3;
    const int cc0 = cp * 2, col0 = hb + cc0;
    float creg[2];
    creg[0] = c0[GRP * HBS + am * HID + col0];
    creg[1] = c0[GRP * HBS + am * HID + col0 + 1];

    const unsigned* cA = cnt;
    const unsigned* cOwn = cnt + GRP * 8 * CNTS;
    unsigned* aOwn = (unsigned*)cOwn;

    const int s_begin = (GRP == 0) ? 0 : 1;
    const int s_end   = (GRP == 0) ? SEQ : SEQ + 1;

    for (int s = s_begin; s < s_end; ++s) {
        // ---- E-prefetch (GRP0; static data, before any wait)  [r9 verbatim] ----
        float ep[4][2];
        if (GRP == 0) {
            const int xv = x[s * BATCH + am];
            const float* Ep = E + (size_t)xv * G4 + col0;
            #pragma unroll
            for (int sec = 0; sec < 4; ++sec) {
                ep[sec][0] = Ep[sec * HID];
                ep[sec][1] = Ep[sec * HID + 1];
            }
        }

        f32x4_t acc[4][2];
        #pragma unroll
        for (int mt = 0; mt < 4; ++mt) {
            acc[mt][0] = f32x4_t{0.f, 0.f, 0.f, 0.f};
            acc[mt][1] = f32x4_t{0.f, 0.f, 0.f, 0.f};
        }

        if (GRP == 0) {
            // ---- single phase: h-GEMM from r0[s] ----
            pollge(cOwn, (unsigned)s * 16u, tid);
            stage_slice((const char*)(rSelf + (size_t)s * HBS), Areg, kByte, l);
            gemm_ks(Areg, Wh, gcol0, gcol1, kg, lm, lk, acc);
        } else {
            // ---- x-phase: r0[s] @ Wih1 (producer far ahead; off own chain) ----
            pollge(cA, (unsigned)s * 16u, tid);
            stage_slice((const char*)(rOther + (size_t)s * HBS), Areg, kByte, l);
            gemm_ks(Areg, Wx, gcol0, gcol1, kg, lm, lk, acc);
            asm volatile("s_waitcnt lgkmcnt(0)" ::: "memory");
            __builtin_amdgcn_sched_barrier(0);
            // ---- h-phase: r1[s-1] @ Whh1 (the recurrence chain) ----
            pollge(cOwn, (unsigned)(s - 1) * 16u, tid);
            stage_slice((const char*)(rSelf + (size_t)(s - 1) * HBS), Areg, kByte, l);
            gemm_ks(Areg, Wh, gcol0, gcol1, kg, lm, lk, acc);
        }

        // ---- 2-slot cross-wave reduction: waves 0,1 write; waves 2,3 RMW ----
        if (kg < 2) {
            #pragma unroll
            for (int mt = 0; mt < 4; ++mt)
                #pragma unroll
                for (int nt = 0; nt < 2; ++nt)
                    #pragma unroll
                    for (int r = 0; r < 4; ++r)
                        pbuf[(kg * 64 + mt * 16 + lk * 4 + r) * 34 + nt * 16 + lm]
                            = acc[mt][nt][r];
        }
        __syncthreads();
        if (kg >= 2) {
            #pragma unroll
            for (int mt = 0; mt < 4; ++mt)
                #pragma unroll
                for (int nt = 0; nt < 2; ++nt)
                    #pragma unroll
                    for (int r = 0; r < 4; ++r) {
                        float* p = &pbuf[((kg - 2) * 64 + mt * 16 + lk * 4 + r) * 34
                                         + nt * 16 + lm];
                        *p += acc[mt][nt][r];
                    }
        }
        __syncthreads();

        // ---- gate assembly + activation + ring write  [r9 pattern] ----
        float g[4][2];
        #pragma unroll
        for (int sec = 0; sec < 4; ++sec) {
            const float* p0 = &pbuf[(0 * 64 + am) * 34 + sec * 8 + cc0];
            const float* p1 = &pbuf[(1 * 64 + am) * 34 + sec * 8 + cc0];
            g[sec][0] = p0[0] + p1[0];
            g[sec][1] = p0[1] + p1[1];
        }
        if (GRP == 0) {
            #pragma unroll
            for (int sec = 0; sec < 4; ++sec) {
                g[sec][0] += ep[sec][0];
                g[sec][1] += ep[sec][1];
            }
        } else {
            #pragma unroll
            for (int sec = 0; sec < 4; ++sec) {
                g[sec][0] += b1[sec * HID + col0];
                g[sec][1] += b1[sec * HID + col0 + 1];
            }
        }

        float hn[2];
        #pragma unroll
        for (int j = 0; j < 2; ++j) {
            float si = sigm(g[0][j]);
            float sf = sigm(g[1][j]);
            float tg = tanhf(g[2][j]);
            float so = sigm(g[3][j]);
            float cn = sf * creg[j] + si * tg;
            hn[j] = so * tanhf(cn);
            creg[j] = cn;
        }
        unsigned short u0 = __builtin_bit_cast(unsigned short, __float2bfloat16(hn[0]));
        unsigned short u1 = __builtin_bit_cast(unsigned short, __float2bfloat16(hn[1]));
        const int wslot = (GRP == 0) ? s + 1 : s;
        cstore4(rSelf + (size_t)wslot * HBS + am * HID + col0,
                (unsigned)u0 | ((unsigned)u1 << 16));

        const bool last = (GRP == 0) ? (s == SEQ - 1) : (s == SEQ);
        if (last) {
            float* oh = out + BATCH * VOCAB + GRP * HBS;
            float* oc = out + BATCH * VOCAB + 2 * HBS + GRP * HBS;
            oh[am * HID + col0]     = hn[0];
            oh[am * HID + col0 + 1] = hn[1];
            oc[am * HID + col0]     = creg[0];
            oc[am * HID + col0 + 1] = creg[1];
        }

        // ---- arrive  [r9 verbatim] ----
        asm volatile("s_waitcnt vmcnt(0)" ::: "memory");
        __syncthreads();
        if (tid == 0)
            __hip_atomic_fetch_add(aOwn + (wg & 7) * CNTS, 1u,
                                   __ATOMIC_RELAXED, __HIP_MEMORY_SCOPE_AGENT);
    }
}

__global__ __launch_bounds__(256, 1) void lstm_persist(
    const int* __restrict__ x,
    const bf16* __restrict__ Whh0, const bf16* __restrict__ Wih1,
    const bf16* __restrict__ Whh1,
    const float* __restrict__ E, const float* __restrict__ b1,
    const float* __restrict__ c0,
    bf16* __restrict__ r0, bf16* __restrict__ r1,
    unsigned* __restrict__ cnt, float* __restrict__ out)
{
    __shared__ char lds[131072 + 2 * 64 * 34 * 4];   // A 128 KB + pbuf 17 KB
    char*  Abuf = lds;
    float* pbuf = (float*)(lds + 131072);
    const int tid = threadIdx.x, wg = blockIdx.x;
    if (wg < 128)
        run_layer<0>(x, nullptr, Whh0, E, nullptr, c0, r0, nullptr, cnt, out,
                     Abuf, pbuf, tid, wg);
    else
        run_layer<1>(x, Wih1, Whh1, E, b1, c0, r1, r0, cnt, out,
                     Abuf, pbuf, tid, wg);
}

// ---------------- FC head ----------------
__global__ void logits_kernel(const float* __restrict__ h, const float* __restrict__ Wfc,
                              const float* __restrict__ bfc, float* __restrict__ out) {
    int t = blockIdx.x * blockDim.x + threadIdx.x;
    if (t >= BATCH * VOCAB) return;
    int m = t >> 7, v = t & 127;
    const float4* hp = reinterpret_cast<const float4*>(h + (size_t)m * HID);
    const float4* wp = reinterpret_cast<const float4*>(Wfc + (size_t)v * HID);
    float acc = 0.f;
    #pragma unroll 4
    for (int k = 0; k < HID / 4; ++k) {
        float4 a = hp[k], w = wp[k];
        acc += a.x * w.x + a.y * w.y + a.z * w.z + a.w * w.w;
    }
    out[t] = acc + bfc[v];
}

// ---------------- launch ----------------
extern "C" void kernel_launch(void* const* d_in, const int* in_sizes, int n_in,
                              void* d_out, int out_size, void* d_ws, size_t ws_size,
                              hipStream_t stream) {
    const int*   x    = (const int*)d_in[0];
    const float* h0   = (const float*)d_in[1];
    const float* c0   = (const float*)d_in[2];
    const float* emb  = (const float*)d_in[3];
    const float* Wih0 = (const float*)d_in[4];
    const float* Whh0 = (const float*)d_in[5];
    const float* b0   = (const float*)d_in[6];
    const float* Wih1 = (const float*)d_in[7];
    const float* Whh1 = (const float*)d_in[8];
    const float* b1   = (const float*)d_in[9];
    const float* Wfc  = (const float*)d_in[10];
    const float* bfc  = (const float*)d_in[11];
    float* out = (float*)d_out;

    char* ws = (char*)d_ws;
    size_t off = 0;
    auto alloc = [&](size_t bytes) -> void* {
        void* p = ws + off;
        off += (bytes + 255) & ~(size_t)255;
        return p;
    };
    bf16*  Whh0_bf = (bf16*)alloc((size_t)G4 * HID * 2);
    bf16*  Wih1_bf = (bf16*)alloc((size_t)G4 * HID * 2);
    bf16*  Whh1_bf = (bf16*)alloc((size_t)G4 * HID * 2);
    float* E       = (float*)alloc((size_t)VOCAB * G4 * 4);
    bf16*  r0      = (bf16*)alloc((size_t)(SEQ + 1) * HBS * 2);   // 32.9 MB ring
    bf16*  r1      = (bf16*)alloc((size_t)(SEQ + 1) * HBS * 2);   // 32.9 MB ring
    unsigned* cnt  = (unsigned*)alloc(16 * CNTS * 4);
    bf16* Wih0_bf  = (bf16*)alloc((size_t)G4 * EMBD * 2);   // dedicated (no overlay)
    bf16* emb_bf   = (bf16*)alloc((size_t)VOCAB * EMBD * 2);
    (void)ws_size; (void)in_sizes; (void)n_in; (void)out_size;

    cast_f32_bf16<<<64,  256, 0, stream>>>(emb,  emb_bf,  VOCAB * EMBD);
    cast_f32_bf16<<<512, 256, 0, stream>>>(Wih0, Wih0_bf, G4 * EMBD);
    cast_f32_bf16<<<512, 256, 0, stream>>>(Whh0, Whh0_bf, G4 * HID);
    cast_f32_bf16<<<512, 256, 0, stream>>>(Wih1, Wih1_bf, G4 * HID);
    cast_f32_bf16<<<512, 256, 0, stream>>>(Whh1, Whh1_bf, G4 * HID);
    init_all<<<64, 256, 0, stream>>>(h0, r0, r1, cnt);
    emb_gemm<<<G4 / 16, 256, 0, stream>>>(emb_bf, Wih0_bf, b0, E);

    lstm_persist<<<256, 256, 0, stream>>>(x, Whh0_bf, Wih1_bf, Whh1_bf,
                                          E, b1, c0, r0, r1, cnt, out);

    logits_kernel<<<(BATCH * VOCAB + 255) / 256, 256, 0, stream>>>(
        out + BATCH * VOCAB + HBS, Wfc, bfc, out);
}

// Round 11
// 2386.766 us; speedup vs baseline: 1.3456x; 1.1295x over previous
//
#include <hip/hip_runtime.h>
#include <hip/hip_bf16.h>

#define SEQ   256
#define BATCH 64
#define HID   1024
#define EMBD  512
#define VOCAB 128
#define G4    4096
#define HBS   (BATCH * HID)      // 65536 elems per ring slot (128 KB bf16)
#define CNTS  32                 // uints between counters (128 B spacing)

typedef short bf16x8_t __attribute__((ext_vector_type(8)));
typedef float f32x4_t  __attribute__((ext_vector_type(4)));
using bf16 = __hip_bfloat16;

__device__ __forceinline__ float sigm(float v) { return 1.f / (1.f + expf(-v)); }

// write-through 4B store (visible at MALL; readers use normal cached loads —
// safe because every ring address is written exactly once per launch)
__device__ __forceinline__ void cstore4(void* p, unsigned d) {
    asm volatile("global_store_dword %0, %1, off sc0 sc1" :: "v"(p), "v"(d) : "memory");
}

// ---------------- casts ----------------
__global__ void cast_f32_bf16(const float* __restrict__ src, bf16* __restrict__ dst, int n) {
    int i = blockIdx.x * blockDim.x + threadIdx.x;
    int stride = gridDim.x * blockDim.x;
    for (; i < n; i += stride) dst[i] = __float2bfloat16(src[i]);
}

// ---------------- init: ring slot 0 + counters ----------------
__global__ void init_all(const float* __restrict__ h0,
                         bf16* __restrict__ r0, bf16* __restrict__ r1,
                         unsigned* __restrict__ cnt) {
    int i = blockIdx.x * blockDim.x + threadIdx.x;
    if (i < 16 * CNTS) cnt[i] = 0u;
    int stride = gridDim.x * blockDim.x;
    for (int k = i; k < HBS; k += stride) {
        r0[k] = __float2bfloat16(h0[k]);
        r1[k] = __float2bfloat16(h0[HBS + k]);
    }
}

// ---------------- E = emb @ Wih0.T + b0   [VOCAB][G4] f32 (validated r2-r10) -
__global__ __launch_bounds__(256) void emb_gemm(
    const bf16* __restrict__ emb_bf, const bf16* __restrict__ Wih0_bf,
    const float* __restrict__ b0, float* __restrict__ E) {
    __shared__ float pb[4 * 128 * 17];
    const int tid = threadIdx.x, l = tid & 63, w = tid >> 6;
    const int lm = l & 15, k8 = (l >> 4) << 3;
    const int colbase = blockIdx.x * 16;
    const int gcol = colbase + lm;
    const int kq = w * 128;

    f32x4_t acc[8];
    #pragma unroll
    for (int rt = 0; rt < 8; ++rt) acc[rt] = f32x4_t{0.f, 0.f, 0.f, 0.f};
    bf16x8_t bf[4];
    #pragma unroll
    for (int k = 0; k < 4; ++k)
        bf[k] = *reinterpret_cast<const bf16x8_t*>(Wih0_bf + gcol * EMBD + kq + k * 32 + k8);
    #pragma unroll
    for (int k = 0; k < 4; ++k)
        #pragma unroll
        for (int rt = 0; rt < 8; ++rt) {
            bf16x8_t a = *reinterpret_cast<const bf16x8_t*>(
                emb_bf + (rt * 16 + lm) * EMBD + kq + k * 32 + k8);
            acc[rt] = __builtin_amdgcn_mfma_f32_16x16x32_bf16(a, bf[k], acc[rt], 0, 0, 0);
        }
    const int r0 = (l >> 4) << 2;
    #pragma unroll
    for (int rt = 0; rt < 8; ++rt)
        #pragma unroll
        for (int r = 0; r < 4; ++r)
            pb[(w * 128 + rt * 16 + r0 + r) * 17 + lm] = acc[rt][r];
    __syncthreads();
    #pragma unroll
    for (int i = 0; i < 8; ++i) {
        int p = tid + i * 256;
        int m = p >> 4, cc = p & 15;
        float g = pb[(0 * 128 + m) * 17 + cc] + pb[(1 * 128 + m) * 17 + cc]
                + pb[(2 * 128 + m) * 17 + cc] + pb[(3 * 128 + m) * 17 + cc];
        E[m * G4 + colbase + cc] = g + b0[colbase + cc];
    }
}

// ---- per-wave A staging: 64 rows x 256 K slice -> LDS via global_load_lds ----
// (validated r10) LDS [64 rows][512 B] linear; bank swizzle via pre-swizzled
// global source chunk: lds chunk (row, kb) holds global chunk (row, kb^(row&7)).
__device__ __forceinline__ void stage_slice(const char* slotB, char* Aregion,
                                            int kByte, int l) {
    #pragma unroll
    for (int i = 0; i < 32; ++i) {
        const int ci  = i * 64 + l;
        const int row = ci >> 5, kb = ci & 31;
        const char* g = slotB + row * 2048 + kByte + ((kb ^ (row & 7)) << 4);
        __builtin_amdgcn_global_load_lds(
            (const __attribute__((address_space(1))) unsigned*)g,
            (__attribute__((address_space(3))) unsigned*)(Aregion + i * 1024),
            16, 0, 0);
    }
}

// ---- W-frag batch issue (static addresses; issued BEFORE polls to hide RTT) --
__device__ __forceinline__ void issue_w(bf16x8_t (&bw)[2][8], const bf16* W,
                                        int gcol0, int gcol1, int kg, int lk) {
    #pragma unroll
    for (int nt = 0; nt < 2; ++nt) {
        const bf16* wb = W + (size_t)(nt == 0 ? gcol0 : gcol1) * HID + kg * 256 + lk * 8;
        #pragma unroll
        for (int kc = 0; kc < 8; ++kc)
            bw[nt][kc] = *reinterpret_cast<const bf16x8_t*>(wb + kc * 32);
    }
}

// ---- K-slice GEMM compute: A from LDS region, W already in regs -------------
__device__ __forceinline__ void gemm_compute(const char* Aregion,
                                             const bf16x8_t (&bw)[2][8],
                                             int lm, int lk, f32x4_t (&acc)[4][2]) {
    asm volatile("s_waitcnt vmcnt(0)" ::: "memory");   // A-DMA + W loads landed
    __builtin_amdgcn_sched_barrier(0);
    #pragma unroll
    for (int kc = 0; kc < 8; ++kc) {
        bf16x8_t a[4];
        #pragma unroll
        for (int mt = 0; mt < 4; ++mt) {
            const int row = mt * 16 + lm;
            a[mt] = *reinterpret_cast<const bf16x8_t*>(
                Aregion + row * 512 + ((kc * 64 + lk * 16) ^ ((row & 7) << 4)));
        }
        #pragma unroll
        for (int mt = 0; mt < 4; ++mt) {
            acc[mt][0] = __builtin_amdgcn_mfma_f32_16x16x32_bf16(a[mt], bw[0][kc], acc[mt][0], 0, 0, 0);
            acc[mt][1] = __builtin_amdgcn_mfma_f32_16x16x32_bf16(a[mt], bw[1][kc], acc[mt][1], 0, 0, 0);
        }
    }
}

// ---- lane-parallel poll: lanes 0-7 read the 8 counters in one VMEM op -------
__device__ __forceinline__ void pollge(const unsigned* base, unsigned target, int tid) {
    if (tid < 64) {
        bool ok = true;
        if (tid < 8)
            ok = (__hip_atomic_load(base + tid * CNTS, __ATOMIC_RELAXED,
                                    __HIP_MEMORY_SCOPE_AGENT) >= target);
        while (!__all((int)ok)) {
            __builtin_amdgcn_s_sleep(1);
            if (tid < 8)
                ok = (__hip_atomic_load(base + tid * CNTS, __ATOMIC_RELAXED,
                                        __HIP_MEMORY_SCOPE_AGENT) >= target);
        }
    }
    __syncthreads();
}

// ---------------- persistent 2-group pipelined LSTM --------------------------
// GRP0 (wg   0..127): L0; s=0..255; r0[s] -> r0[s+1]; free-runs (own flags only)
// GRP1 (wg 128..255): L1; s=1..256; x: r0[s] (GRP0 ahead; stage+W hidden under
//                     own-chain poll), h: r1[s-1] -> r1[s]
template<int GRP>
__device__ __forceinline__ void run_layer(
    const int* __restrict__ x,
    const bf16* __restrict__ Wx, const bf16* __restrict__ Wh,
    const float* __restrict__ E, const float* __restrict__ b1,
    const float* __restrict__ c0,
    bf16* __restrict__ rSelf, const bf16* __restrict__ rOther,
    unsigned* __restrict__ cnt, float* __restrict__ out,
    char* __restrict__ Abuf, float* __restrict__ pbuf, int tid, int wg)
{
    const int gl = wg & 127;
    const int hb = gl * 8;                       // 8 h-cols per WG
    const int l  = tid & 63, kg = tid >> 6;      // wave = K-slice group (256 wide)
    const int lm = l & 15, lk = l >> 4;
    char* Areg = Abuf + kg * 32768;              // wave-private 32 KB
    const int kByte = kg * 512;

    // gate columns (weight rows): tile nt covers sections 2nt + (lm>>3)  [r9/r10]
    const int gcol0 = (0 + (lm >> 3)) * HID + hb + (lm & 7);
    const int gcol1 = (2 + (lm >> 3)) * HID + hb + (lm & 7);

    // activation mapping: thread -> (row am, 2 h-cols)  [r9/r10 verbatim]
    const int am = tid >> 2, cp = tid & 3;
    const int cc0 = cp * 2, col0 = hb + cc0;
    float creg[2];
    creg[0] = c0[GRP * HBS + am * HID + col0];
    creg[1] = c0[GRP * HBS + am * HID + col0 + 1];

    const unsigned* cA = cnt;
    const unsigned* cOwn = cnt + GRP * 8 * CNTS;
    unsigned* aOwn = (unsigned*)cOwn;

    const int s_begin = (GRP == 0) ? 0 : 1;
    const int s_end   = (GRP == 0) ? SEQ : SEQ + 1;

    for (int s = s_begin; s < s_end; ++s) {
        // ---- E-prefetch (GRP0; static data, before any wait)  [r10 verbatim] ----
        float ep[4][2];
        if (GRP == 0) {
            const int xv = x[s * BATCH + am];
            const float* Ep = E + (size_t)xv * G4 + col0;
            #pragma unroll
            for (int sec = 0; sec < 4; ++sec) {
                ep[sec][0] = Ep[sec * HID];
                ep[sec][1] = Ep[sec * HID + 1];
            }
        }

        f32x4_t acc[4][2];
        #pragma unroll
        for (int mt = 0; mt < 4; ++mt) {
            acc[mt][0] = f32x4_t{0.f, 0.f, 0.f, 0.f};
            acc[mt][1] = f32x4_t{0.f, 0.f, 0.f, 0.f};
        }

        if (GRP == 0) {
            // W batch issued pre-poll (static addrs): RTT hides under poll spin
            bf16x8_t bw[2][8];
            issue_w(bw, Wh, gcol0, gcol1, kg, lk);
            pollge(cOwn, (unsigned)s * 16u, tid);
            stage_slice((const char*)(rSelf + (size_t)s * HBS), Areg, kByte, l);
            gemm_compute(Areg, bw, lm, lk, acc);
        } else {
            // ---- x-phase hoisted OFF the chain: issue Wx + x-stage before the
            //      own-chain poll; their RTTs hide under the poll spin ----
            bf16x8_t bw[2][8];
            issue_w(bw, Wx, gcol0, gcol1, kg, lk);
            pollge(cA, (unsigned)s * 16u, tid);            // instant: GRP0 ahead
            stage_slice((const char*)(rOther + (size_t)s * HBS), Areg, kByte, l);
            pollge(cOwn, (unsigned)(s - 1) * 16u, tid);    // the real wait
            gemm_compute(Areg, bw, lm, lk, acc);           // x-data already landed
            asm volatile("s_waitcnt lgkmcnt(0)" ::: "memory");
            __builtin_amdgcn_sched_barrier(0);
            // ---- h-phase: the irreducible chain RTT ----
            issue_w(bw, Wh, gcol0, gcol1, kg, lk);
            stage_slice((const char*)(rSelf + (size_t)(s - 1) * HBS), Areg, kByte, l);
            gemm_compute(Areg, bw, lm, lk, acc);
        }

        // ---- 2-slot cross-wave reduction  [r10 verbatim] ----
        if (kg < 2) {
            #pragma unroll
            for (int mt = 0; mt < 4; ++mt)
                #pragma unroll
                for (int nt = 0; nt < 2; ++nt)
                    #pragma unroll
                    for (int r = 0; r < 4; ++r)
                        pbuf[(kg * 64 + mt * 16 + lk * 4 + r) * 34 + nt * 16 + lm]
                            = acc[mt][nt][r];
        }
        __syncthreads();
        if (kg >= 2) {
            #pragma unroll
            for (int mt = 0; mt < 4; ++mt)
                #pragma unroll
                for (int nt = 0; nt < 2; ++nt)
                    #pragma unroll
                    for (int r = 0; r < 4; ++r) {
                        float* p = &pbuf[((kg - 2) * 64 + mt * 16 + lk * 4 + r) * 34
                                         + nt * 16 + lm];
                        *p += acc[mt][nt][r];
                    }
        }
        __syncthreads();

        // ---- gate assembly + activation + ring write  [r10 verbatim] ----
        float g[4][2];
        #pragma unroll
        for (int sec = 0; sec < 4; ++sec) {
            const float* p0 = &pbuf[(0 * 64 + am) * 34 + sec * 8 + cc0];
            const float* p1 = &pbuf[(1 * 64 + am) * 34 + sec * 8 + cc0];
            g[sec][0] = p0[0] + p1[0];
            g[sec][1] = p0[1] + p1[1];
        }
        if (GRP == 0) {
            #pragma unroll
            for (int sec = 0; sec < 4; ++sec) {
                g[sec][0] += ep[sec][0];
                g[sec][1] += ep[sec][1];
            }
        } else {
            #pragma unroll
            for (int sec = 0; sec < 4; ++sec) {
                g[sec][0] += b1[sec * HID + col0];
                g[sec][1] += b1[sec * HID + col0 + 1];
            }
        }

        float hn[2];
        #pragma unroll
        for (int j = 0; j < 2; ++j) {
            float si = sigm(g[0][j]);
            float sf = sigm(g[1][j]);
            float tg = tanhf(g[2][j]);
            float so = sigm(g[3][j]);
            float cn = sf * creg[j] + si * tg;
            hn[j] = so * tanhf(cn);
            creg[j] = cn;
        }
        unsigned short u0 = __builtin_bit_cast(unsigned short, __float2bfloat16(hn[0]));
        unsigned short u1 = __builtin_bit_cast(unsigned short, __float2bfloat16(hn[1]));
        const int wslot = (GRP == 0) ? s + 1 : s;
        cstore4(rSelf + (size_t)wslot * HBS + am * HID + col0,
                (unsigned)u0 | ((unsigned)u1 << 16));

        const bool last = (GRP == 0) ? (s == SEQ - 1) : (s == SEQ);
        if (last) {
            float* oh = out + BATCH * VOCAB + GRP * HBS;
            float* oc = out + BATCH * VOCAB + 2 * HBS + GRP * HBS;
            oh[am * HID + col0]     = hn[0];
            oh[am * HID + col0 + 1] = hn[1];
            oc[am * HID + col0]     = creg[0];
            oc[am * HID + col0 + 1] = creg[1];
        }

        // ---- arrive  [r10 verbatim] ----
        asm volatile("s_waitcnt vmcnt(0)" ::: "memory");
        __syncthreads();
        if (tid == 0)
            __hip_atomic_fetch_add(aOwn + (wg & 7) * CNTS, 1u,
                                   __ATOMIC_RELAXED, __HIP_MEMORY_SCOPE_AGENT);
    }
}

__global__ __launch_bounds__(256, 1) void lstm_persist(
    const int* __restrict__ x,
    const bf16* __restrict__ Whh0, const bf16* __restrict__ Wih1,
    const bf16* __restrict__ Whh1,
    const float* __restrict__ E, const float* __restrict__ b1,
    const float* __restrict__ c0,
    bf16* __restrict__ r0, bf16* __restrict__ r1,
    unsigned* __restrict__ cnt, float* __restrict__ out)
{
    __shared__ char lds[131072 + 2 * 64 * 34 * 4];   // A 128 KB + pbuf 17 KB
    char*  Abuf = lds;
    float* pbuf = (float*)(lds + 131072);
    const int tid = threadIdx.x, wg = blockIdx.x;
    if (wg < 128)
        run_layer<0>(x, nullptr, Whh0, E, nullptr, c0, r0, nullptr, cnt, out,
                     Abuf, pbuf, tid, wg);
    else
        run_layer<1>(x, Wih1, Whh1, E, b1, c0, r1, r0, cnt, out,
                     Abuf, pbuf, tid, wg);
}

// ---------------- FC head ----------------
__global__ void logits_kernel(const float* __restrict__ h, const float* __restrict__ Wfc,
                              const float* __restrict__ bfc, float* __restrict__ out) {
    int t = blockIdx.x * blockDim.x + threadIdx.x;
    if (t >= BATCH * VOCAB) return;
    int m = t >> 7, v = t & 127;
    const float4* hp = reinterpret_cast<const float4*>(h + (size_t)m * HID);
    const float4* wp = reinterpret_cast<const float4*>(Wfc + (size_t)v * HID);
    float acc = 0.f;
    #pragma unroll 4
    for (int k = 0; k < HID / 4; ++k) {
        float4 a = hp[k], w = wp[k];
        acc += a.x * w.x + a.y * w.y + a.z * w.z + a.w * w.w;
    }
    out[t] = acc + bfc[v];
}

// ---------------- launch ----------------
extern "C" void kernel_launch(void* const* d_in, const int* in_sizes, int n_in,
                              void* d_out, int out_size, void* d_ws, size_t ws_size,
                              hipStream_t stream) {
    const int*   x    = (const int*)d_in[0];
    const float* h0   = (const float*)d_in[1];
    const float* c0   = (const float*)d_in[2];
    const float* emb  = (const float*)d_in[3];
    const float* Wih0 = (const float*)d_in[4];
    const float* Whh0 = (const float*)d_in[5];
    const float* b0   = (const float*)d_in[6];
    const float* Wih1 = (const float*)d_in[7];
    const float* Whh1 = (const float*)d_in[8];
    const float* b1   = (const float*)d_in[9];
    const float* Wfc  = (const float*)d_in[10];
    const float* bfc  = (const float*)d_in[11];
    float* out = (float*)d_out;

    char* ws = (char*)d_ws;
    size_t off = 0;
    auto alloc = [&](size_t bytes) -> void* {
        void* p = ws + off;
        off += (bytes + 255) & ~(size_t)255;
        return p;
    };
    bf16*  Whh0_bf = (bf16*)alloc((size_t)G4 * HID * 2);
    bf16*  Wih1_bf = (bf16*)alloc((size_t)G4 * HID * 2);
    bf16*  Whh1_bf = (bf16*)alloc((size_t)G4 * HID * 2);
    float* E       = (float*)alloc((size_t)VOCAB * G4 * 4);
    bf16*  r0      = (bf16*)alloc((size_t)(SEQ + 1) * HBS * 2);   // 32.9 MB ring
    bf16*  r1      = (bf16*)alloc((size_t)(SEQ + 1) * HBS * 2);   // 32.9 MB ring
    unsigned* cnt  = (unsigned*)alloc(16 * CNTS * 4);
    bf16* Wih0_bf  = (bf16*)alloc((size_t)G4 * EMBD * 2);   // dedicated (no overlay)
    bf16* emb_bf   = (bf16*)alloc((size_t)VOCAB * EMBD * 2);
    (void)ws_size; (void)in_sizes; (void)n_in; (void)out_size;

    cast_f32_bf16<<<64,  256, 0, stream>>>(emb,  emb_bf,  VOCAB * EMBD);
    cast_f32_bf16<<<512, 256, 0, stream>>>(Wih0, Wih0_bf, G4 * EMBD);
    cast_f32_bf16<<<512, 256, 0, stream>>>(Whh0, Whh0_bf, G4 * HID);
    cast_f32_bf16<<<512, 256, 0, stream>>>(Wih1, Wih1_bf, G4 * HID);
    cast_f32_bf16<<<512, 256, 0, stream>>>(Whh1, Whh1_bf, G4 * HID);
    init_all<<<64, 256, 0, stream>>>(h0, r0, r1, cnt);
    emb_gemm<<<G4 / 16, 256, 0, stream>>>(emb_bf, Wih0_bf, b0, E);

    lstm_persist<<<256, 256, 0, stream>>>(x, Whh0_bf, Wih1_bf, Whh1_bf,
                                          E, b1, c0, r0, r1, cnt, out);

    logits_kernel<<<(BATCH * VOCAB + 255) / 256, 256, 0, stream>>>(
        out + BATCH * VOCAB + HBS, Wfc, bfc, out);
}